// Round 7
// baseline (93.353 us; speedup 1.0000x reference)
//
#include <hip/hip_runtime.h>

// Fused grouped 1x1 conv (q,k,v) + 5x5 reflect-window per-channel softmax attention.
// x: (2,128,96,96) f32; wq/wk/wv: (4,32,32) f32; out: (2,128,96,96) f32.
// Block = (8x8 tile, group, batch), 256 thr = 4 waves; wave owns 8 out-channels.
//
// R7 = R6 + DIAGNOSTIC: phase 3 executed twice (serial pass loop, kvb pointer
// laundered through empty asm so loads can't be CSE'd; output = final pass, so
// semantics identical). Purpose: dur delta isolates phase-3's true marginal
// cost, and pushing the kernel past the 41us harness fills makes its rocprof
// counters visible again. Everything else is byte-identical to R6.

#define HW 96
#define RG 12
#define NPOS 144
#define CSTR 36            // dwords per position row in kvb (32 ch + 4 pad; 144B = 16B-aligned)

typedef _Float16 half8  __attribute__((ext_vector_type(8)));
typedef _Float16 half2v __attribute__((ext_vector_type(2)));
typedef float    float4v __attribute__((ext_vector_type(4)));
typedef unsigned int uint4v __attribute__((ext_vector_type(4)));

__device__ __forceinline__ int refl(int i) {
    i = (i < 0) ? -i : i;          // reflect (edge excluded): -1->1, -2->2
    i = (i > 95) ? (190 - i) : i;  // 96->94, 97->93
    return i;
}

__global__ __launch_bounds__(256) void fused_attn(
    const float* __restrict__ x, const float* __restrict__ wq,
    const float* __restrict__ wk, const float* __restrict__ wv,
    float* __restrict__ out)
{
    // xs: f16 [144 pos][32 ch] = 9216 B (dead after phase 2; qs aliases it)
    // kvb: [144 pos][36 dwords] (k lo16 | v hi16 per ch, 32 used) = 20736 B
    __shared__ alignas(16) unsigned char smem[9216 + 20736];
    _Float16*     xs  = (_Float16*)smem;
    unsigned int* kvb = (unsigned int*)(smem + 9216);
    _Float16*     qs  = (_Float16*)smem;        // alias: [64 px][32 ch] f16, 4 KB

    const int tid = threadIdx.x;
    const int g = blockIdx.y, b = blockIdx.z;
    const int h0 = (blockIdx.x / 12) * 8;
    const int w0 = (blockIdx.x % 12) * 8;
    const float* xg = x + (size_t)(b * 128 + g * 32) * (HW * HW);

    // ---- Phase 1: coalesced staging (aligned float4 row loads; 16 cols cover 12) ----
    const int wA   = min(max(w0 - 4, 0), 80);
    const int colB = wA - w0 + 2;                // region col of first loaded float
    #pragma unroll
    for (int it = 0; it < 6; it++) {
        int idx = it * 256 + tid;                // 1536 = 32ch x 12row x 4seg
        int seg = idx & 3;
        int pr  = idx >> 2;
        int ch  = pr & 31;
        int row = pr >> 5;
        int iy  = refl(h0 + row - 2);
        const float4v f4 = *(const float4v*)(xg + ch * (HW * HW) + iy * HW + wA + seg * 4);
        int col0 = colB + seg * 4;
        #pragma unroll
        for (int e = 0; e < 4; e++) {
            int col = col0 + e;
            if (col >= 0 && col < RG)
                xs[(row * RG + col) * 32 + ch] = (_Float16)f4[e];
        }
    }

    // ---- Weight B-fragments (global loads in flight across the barrier) ----
    const int wid  = tid >> 6;
    const int lane = tid & 63;
    const int n0   = wid * 8;          // this wave's channel base
    const int col  = lane & 15;        // MFMA n / m index
    const int quad = lane >> 4;        // 0..3
    const int koff = quad * 8;         // K offset of this lane's 8 f16

    const float* wrow = (col < 8) ? (wk + (g * 32 + n0 + col) * 32)
                                  : (wv + (g * 32 + n0 + col - 8) * 32);
    half8 bkv;
    #pragma unroll
    for (int j = 0; j < 8; j++)
        bkv[j] = (_Float16)wrow[koff + j];

    half8 bq = {0, 0, 0, 0, 0, 0, 0, 0};   // cols 8-15 zero
    if (col < 8) {
        const float* qr = wq + (g * 32 + n0 + col) * 32;
        #pragma unroll
        for (int j = 0; j < 8; j++)
            bq[j] = (_Float16)(qr[koff + j] * 1.44269504f);  // fold log2(e) into wq
    }

    // ---- Reflect halo columns for edge tiles (in-LDS copy) ----
    if (w0 == 0 || w0 == 88) {
        __syncthreads();                         // staging writes visible
        const int left = (w0 == 0);
        for (int it = 0; it < 3; it++) {
            int idx = it * 256 + tid;            // 768 = 32ch x 12row x 2cols
            int ch  = idx & 31;
            int rr  = idx >> 5;                  // 0..23
            int row = rr >> 1, wc = rr & 1;
            int dstc = left ? wc : (10 + wc);      // L: {0,1}  R: {10,11}
            int srcc = left ? (4 - wc) : (8 - wc); // L: {4,3} R: {8,7}
            xs[(row * RG + dstc) * 32 + ch] = xs[(row * RG + srcc) * 32 + ch];
        }
    }
    __syncthreads();

    // ---- Phase 2a: k,v conv — 9 MFMAs cover 144 positions x 16 (k8+v8) ----
    _Float16* kv16 = (_Float16*)kvb;
    #pragma unroll
    for (int t = 0; t < 9; t++) {
        int pa = t * 16 + col;                      // A row m -> region pos
        half8 a = *(const half8*)&xs[pa * 32 + koff];
        float4v d = {0.f, 0.f, 0.f, 0.f};
        d = __builtin_amdgcn_mfma_f32_16x16x32_f16(a, bkv, d, 0, 0, 0);
        // D: col = ch/type (n), rows quad*4+r = pos within tile-of-16
        int c    = n0 + (col & 7);
        int half_ = col >> 3;                       // k -> lo16, v -> hi16
        #pragma unroll
        for (int r = 0; r < 4; r++) {
            int p = t * 16 + quad * 4 + r;
            kv16[(p * CSTR + c) * 2 + half_] = (_Float16)d[r];
        }
    }

    // ---- Phase 2b: q conv — 4 MFMAs over the 64 center pixels (results in regs) ----
    float4v dqv[4];
    #pragma unroll
    for (int t = 0; t < 4; t++) {
        int mp = t * 16 + col;                      // center pixel id 0..63
        int p  = ((mp >> 3) + 2) * RG + (mp & 7) + 2;
        half8 a = *(const half8*)&xs[p * 32 + koff];
        float4v z = {0.f, 0.f, 0.f, 0.f};
        dqv[t] = __builtin_amdgcn_mfma_f32_16x16x32_f16(a, bq, z, 0, 0, 0);
    }

    __syncthreads();   // all xs reads done -> safe to overwrite with qs

    if (col < 8) {
        #pragma unroll
        for (int t = 0; t < 4; t++) {
            #pragma unroll
            for (int r = 0; r < 4; r++) {
                int pix = t * 16 + quad * 4 + r;
                qs[pix * 32 + n0 + col] = (_Float16)dqv[t][r];
            }
        }
    }
    __syncthreads();

    // ---- Phase 3: 25-tap softmax, all 8 channels; lane = pixel ----
    // DIAGNOSTIC: executed twice; pass loop is serial (unroll 1) and the kvb
    // pointer is laundered through empty asm so pass-2 loads re-issue.
    const int ty = lane >> 3, tx = lane & 7;

    half8 qh = *(const half8*)&qs[lane * 32 + n0];  // 1 ds_read_b128
    float qf[8];
    #pragma unroll
    for (int c = 0; c < 8; c++) qf[c] = (float)qh[c];   // pre-scaled by log2e

    float den[8], num[8];
    const unsigned int* kvp = kvb;

    #pragma unroll 1
    for (int pass = 0; pass < 2; pass++) {
        asm volatile("" : "+v"(kvp));   // opaque: blocks CSE between passes
        #pragma unroll
        for (int c = 0; c < 8; c++) { den[c] = 0.f; num[c] = 0.f; }

        #pragma unroll
        for (int dy = 0; dy < 5; dy++) {
            const unsigned int* base = &kvp[((ty + dy) * RG + tx) * CSTR + n0];
            uint4v t0[5], t1[5];
            #pragma unroll
            for (int dx = 0; dx < 5; dx++) {            // 10 ds_read_b128 batched
                t0[dx] = *(const uint4v*)(base + dx * CSTR);
                t1[dx] = *(const uint4v*)(base + dx * CSTR + 4);
            }
            #pragma unroll
            for (int dx = 0; dx < 5; dx++) {
                #pragma unroll
                for (int c = 0; c < 8; c++) {
                    unsigned int u = (c < 4) ? t0[dx][c] : t1[dx][c - 4];
                    half2v kv = __builtin_bit_cast(half2v, u);
                    float e = __builtin_amdgcn_exp2f(qf[c] * (float)kv[0]);
                    den[c] += e;
                    num[c] = fmaf(e, (float)kv[1], num[c]);
                }
            }
        }
    }

    float* outp = out + (size_t)((b * 128 + g * 32 + n0) * HW + (h0 + ty)) * HW + (w0 + tx);
    #pragma unroll
    for (int c = 0; c < 8; c++)
        outp[c * (HW * HW)] = num[c] * __builtin_amdgcn_rcpf(den[c]);
}

extern "C" void kernel_launch(void* const* d_in, const int* in_sizes, int n_in,
                              void* d_out, int out_size, void* d_ws, size_t ws_size,
                              hipStream_t stream) {
    const float* x  = (const float*)d_in[0];
    const float* wq = (const float*)d_in[1];
    const float* wk = (const float*)d_in[2];
    const float* wv = (const float*)d_in[3];
    float* out = (float*)d_out;

    dim3 grid(144, 4, 2);   // (spatial tiles, groups, batch)
    fused_attn<<<grid, 256, 0, stream>>>(x, wq, wk, wv, out);
}

// Round 8
// 90.554 us; speedup vs baseline: 1.0309x; 1.0309x over previous
//
#include <hip/hip_runtime.h>

// R8: structural split into two kernels.
//  A (conv_qkv): LDS-free per-wave MFMA GEMM. Reads x exactly once (coalesced
//    64B segments), writes q (pre-scaled by log2e), k, v as [px][32ch] f16
//    planes into d_ws. No barriers.
//  B (attn): per 8x8 tile stages k/v 12-row region via CONTIGUOUS 1KB-per-row
//    reads (channel-contiguous layout fixes the 32-plane scatter of R2..R7;
//    data is L2/L3-warm from A), interleaves into R6's kvb (k|v<<16, stride 36
//    dwords), then phase 3 verbatim R6. 1 barrier interior, 2 for edge tiles.
// Rationale: R7 diagnostic showed phase 3 is ~free (absorbed in stalls);
// the ~36us kernel was phase-1/2 latency structure, which this removes.

#define HW 96
#define RG 12
#define CSTR 36            // dwords per position in kvb (32 ch + 4 pad)
#define PXN 9216           // 96*96

typedef _Float16 half8  __attribute__((ext_vector_type(8)));
typedef _Float16 half2v __attribute__((ext_vector_type(2)));
typedef float    float4v __attribute__((ext_vector_type(4)));
typedef unsigned int uint4v __attribute__((ext_vector_type(4)));

__device__ __forceinline__ int refl(int i) {
    i = (i < 0) ? -i : i;          // reflect (edge excluded): -1->1, -2->2
    i = (i > 95) ? (190 - i) : i;  // 96->94, 97->93
    return i;
}

// ---------------- Kernel A: q,k,v grouped 1x1 conv via MFMA ----------------
// grid (72, 4, 2): 128 px per block, wave = 32 px, 6 cout-tiles (q,k,v x2).
__global__ __launch_bounds__(256) void conv_qkv(
    const float* __restrict__ x, const float* __restrict__ wq,
    const float* __restrict__ wk, const float* __restrict__ wv,
    _Float16* __restrict__ qp, _Float16* __restrict__ kp, _Float16* __restrict__ vp)
{
    const int tid  = threadIdx.x;
    const int g = blockIdx.y, b = blockIdx.z;
    const int lane = tid & 63, wid = tid >> 6;
    const int col  = lane & 15;        // MFMA m/n index
    const int quad = lane >> 4;
    const int koff = quad * 8;
    const int pxw  = blockIdx.x * 128 + wid * 32;   // wave's 32-px base
    const float* xg = x + (size_t)(b * 128 + g * 32) * PXN;
    const size_t plane = (size_t)(b * 4 + g) * PXN * 32;

    // 6 B-fragments: T = type*2+sub; type 0=q (scaled by log2e), 1=k, 2=v
    const float* wsrc[3] = {wq, wk, wv};
    half8 frag[6];
    #pragma unroll
    for (int T = 0; T < 6; T++) {
        const float* wr = wsrc[T >> 1] + (g * 32 + (T & 1) * 16 + col) * 32 + koff;
        float sc = (T < 2) ? 1.44269504f : 1.0f;
        #pragma unroll
        for (int j = 0; j < 8; j++) frag[T][j] = (_Float16)(wr[j] * sc);
    }

    _Float16* outp[3] = {qp, kp, vp};
    #pragma unroll
    for (int s = 0; s < 2; s++) {
        int apx = pxw + s * 16 + col;               // A-frag row m = col
        half8 a;
        #pragma unroll
        for (int j = 0; j < 8; j++)                 // coalesced: 4x64B segs/instr
            a[j] = (_Float16)xg[(koff + j) * PXN + apx];
        #pragma unroll
        for (int T = 0; T < 6; T++) {
            float4v d = {0.f, 0.f, 0.f, 0.f};
            d = __builtin_amdgcn_mfma_f32_16x16x32_f16(a, frag[T], d, 0, 0, 0);
            _Float16* pl = outp[T >> 1];
            #pragma unroll
            for (int r = 0; r < 4; r++) {           // D: col=cout, row=quad*4+r=px
                int dpx = pxw + s * 16 + quad * 4 + r;
                pl[plane + (size_t)dpx * 32 + (T & 1) * 16 + col] = (_Float16)d[r];
            }
        }
    }
}

// ---------------- Kernel B: 5x5 window softmax attention ----------------
// grid (144, 4, 2): 8x8 tile; wave owns 8 channels; phase 3 = R6 verbatim.
__global__ __launch_bounds__(256) void attn(
    const _Float16* __restrict__ qp, const _Float16* __restrict__ kp,
    const _Float16* __restrict__ vp, float* __restrict__ out)
{
    __shared__ unsigned int kvb[144 * CSTR];   // k|v<<16 per (pos,ch), 20736 B

    const int tid = threadIdx.x;
    const int g = blockIdx.y, b = blockIdx.z;
    const int h0 = (blockIdx.x / 12) * 8;
    const int w0 = (blockIdx.x % 12) * 8;
    const int lane = tid & 63, wid = tid >> 6, n0 = wid * 8;
    const int ty = lane >> 3, tx = lane & 7;
    const size_t plane = (size_t)(b * 4 + g) * PXN * 32;

    // q for this lane's pixel (8 ch, 16B) — issue before staging waits
    const int qpx = (h0 + ty) * HW + (w0 + tx);
    uint4v qu = *(const uint4v*)(qp + plane + (size_t)qpx * 32 + n0);

    // ---- stage k,v rows -> interleaved kvb. Wave = one full 1KB row of k and v.
    const int wA  = min(max(w0 - 4, 0), 80);
    const int off = w0 - 2 - wA;               // lds col s = px_i - off
    #pragma unroll
    for (int it = 0; it < 3; it++) {
        int idx  = it * 256 + tid;             // 768 = 12 rows x 16 px x 4 chunks
        int chunk = idx & 3, px_i = (idx >> 2) & 15, row = idx >> 6;
        int iy = refl(h0 + row - 2);
        size_t gaddr = plane + (size_t)(iy * HW + wA + px_i) * 32 + chunk * 8;
        uint4v kq = *(const uint4v*)(kp + gaddr);
        uint4v vq = *(const uint4v*)(vp + gaddr);
        int s = px_i - off;
        if (s >= 0 && s < RG) {
            int base = (row * RG + s) * CSTR + chunk * 8;
            #pragma unroll
            for (int e = 0; e < 4; e++) {
                kvb[base + 2 * e]     = __builtin_amdgcn_perm(vq[e], kq[e], 0x05040100);
                kvb[base + 2 * e + 1] = __builtin_amdgcn_perm(vq[e], kq[e], 0x07060302);
            }
        }
    }
    __syncthreads();

    // ---- reflect fixup for edge columns (block-uniform branch) ----
    if (off != 2) {
        const int left = (w0 == 0);
        #pragma unroll
        for (int it = 0; it < 3; it++) {
            int idx = it * 256 + tid;          // 768 = 12 rows x 2 cols x 32 ch
            int ch = idx & 31, rr = idx >> 5;
            int row = rr >> 1, wc = rr & 1;
            int dst = left ? wc : (10 + wc);
            int src = left ? (4 - wc) : (8 - wc);
            kvb[(row * RG + dst) * CSTR + ch] = kvb[(row * RG + src) * CSTR + ch];
        }
        __syncthreads();
    }

    // ---- phase 3: 25-tap softmax, 8 channels; lane = pixel (R6 verbatim) ----
    half8 qh = __builtin_bit_cast(half8, qu);
    float qf[8];
    #pragma unroll
    for (int c = 0; c < 8; c++) qf[c] = (float)qh[c];   // pre-scaled by log2e

    float den[8], num[8];
    #pragma unroll
    for (int c = 0; c < 8; c++) { den[c] = 0.f; num[c] = 0.f; }

    #pragma unroll
    for (int dy = 0; dy < 5; dy++) {
        const unsigned int* base = &kvb[((ty + dy) * RG + tx) * CSTR + n0];
        uint4v t0[5], t1[5];
        #pragma unroll
        for (int dx = 0; dx < 5; dx++) {            // 10 ds_read_b128 batched
            t0[dx] = *(const uint4v*)(base + dx * CSTR);
            t1[dx] = *(const uint4v*)(base + dx * CSTR + 4);
        }
        #pragma unroll
        for (int dx = 0; dx < 5; dx++) {
            #pragma unroll
            for (int c = 0; c < 8; c++) {
                unsigned int u = (c < 4) ? t0[dx][c] : t1[dx][c - 4];
                half2v kv = __builtin_bit_cast(half2v, u);
                float e = __builtin_amdgcn_exp2f(qf[c] * (float)kv[0]);
                den[c] += e;
                num[c] = fmaf(e, (float)kv[1], num[c]);
            }
        }
    }

    float* outp = out + (size_t)((b * 128 + g * 32 + n0) * HW + (h0 + ty)) * HW + (w0 + tx);
    #pragma unroll
    for (int c = 0; c < 8; c++)
        outp[c * (HW * HW)] = num[c] * __builtin_amdgcn_rcpf(den[c]);
}

extern "C" void kernel_launch(void* const* d_in, const int* in_sizes, int n_in,
                              void* d_out, int out_size, void* d_ws, size_t ws_size,
                              hipStream_t stream) {
    const float* x  = (const float*)d_in[0];
    const float* wq = (const float*)d_in[1];
    const float* wk = (const float*)d_in[2];
    const float* wv = (const float*)d_in[3];
    float* out = (float*)d_out;

    const size_t PLSZ = (size_t)2 * 4 * PXN * 32;   // elements per f16 plane-set
    _Float16* qp = (_Float16*)d_ws;
    _Float16* kp = qp + PLSZ;
    _Float16* vp = kp + PLSZ;

    conv_qkv<<<dim3(72, 4, 2), 256, 0, stream>>>(x, wq, wk, wv, qp, kp, vp);
    attn<<<dim3(144, 4, 2), 256, 0, stream>>>(qp, kp, vp, out);
}